// Round 2
// baseline (672.719 us; speedup 1.0000x reference)
//
#include <hip/hip_runtime.h>
#include <math.h>

// CepstrumToImpulseResponse: h[0]=exp(c[0]); h[n] = (1/n) * sum_{m=1}^{min(n,99)} m*c[m]*h[n-m]
// B=65536, M=99 (CEP_ORDER), N=512 (IR_LENGTH). Output float32 [B, N].
//
// One thread per batch element. w[99] (weighted cepstrum) and h[99] (history
// shift register) live in VGPRs with fully static indexing. Time loop unrolled
// by U=7 (511 = 7*73) so the history shift is amortized over 7 steps.
//
// Round-2 change: allow the allocator the full 512-VGPR unified file
// (amdgpu_waves_per_eu(1,1)) -- round 1 capped at 256 arch VGPRs and spilled
// ~10 slots to scratch (WRITE_SIZE 291 MB vs 134 MB ideal), which at
// 1 wave/SIMD was fully-exposed latency (13x over issue-bound).

#define BATCH     65536
#define CEP_M     99
#define IR_N      512
#define UNROLL_U  7
#define NGROUPS   73   // (IR_N - 1) / UNROLL_U == 511/7

__global__
__attribute__((amdgpu_flat_work_group_size(256, 256), amdgpu_waves_per_eu(1, 1)))
void cep2ir_kernel(const float* __restrict__ c, float* __restrict__ out) {
    const int b = blockIdx.x * 256 + threadIdx.x;
    const float* cb = c + (size_t)b * (CEP_M + 1);
    float* ob = out + (size_t)b * IR_N;

    // w[m-1] = m * c[m], m = 1..99, computed directly from float4 loads
    // (no cc[] staging array -> lower peak register pressure).
    float w[CEP_M];
    float c0;
    {
        const float4* cb4 = reinterpret_cast<const float4*>(cb);
        float4 v = cb4[0];
        c0 = v.x;
        w[0] = v.y * 1.0f;
        w[1] = v.z * 2.0f;
        w[2] = v.w * 3.0f;
#pragma unroll
        for (int i = 1; i < (CEP_M + 1) / 4; ++i) {
            v = cb4[i];
            w[4 * i - 1] = v.x * (float)(4 * i + 0);
            w[4 * i + 0] = v.y * (float)(4 * i + 1);
            w[4 * i + 1] = v.z * (float)(4 * i + 2);
            w[4 * i + 2] = v.w * (float)(4 * i + 3);
        }
    }

    const float h0 = expf(c0);
    ob[0] = h0;

    // h[k] = h[n-1-k]; zeros stand in for negative time indices.
    float h[CEP_M];
#pragma unroll
    for (int i = 0; i < CEP_M; ++i) h[i] = 0.0f;
    h[0] = h0;

    float fn = 1.0f;  // float value of n for step j=0 of the current group
#pragma unroll 1
    for (int g = 0; g < NGROUPS; ++g) {
        float s[UNROLL_U];
        float* og = ob + 1 + g * UNROLL_U;
#pragma unroll
        for (int j = 0; j < UNROLL_U; ++j) {
            // h(n+j-m): for m <= j it's s[j-m] (this group), else h[m-1-j].
            float a[4] = {0.0f, 0.0f, 0.0f, 0.0f};
#pragma unroll
            for (int m = j + 1; m <= CEP_M; ++m)
                a[m & 3] += w[m - 1] * h[m - 1 - j];
#pragma unroll
            for (int m = 1; m <= j; ++m)
                a[m & 3] += w[m - 1] * s[j - m];
            const float t = (a[0] + a[1]) + (a[2] + a[3]);
            const float rn = __builtin_amdgcn_rcpf(fn + (float)j);
            s[j] = t * rn;
            og[j] = s[j];
        }
        // Shift history by U: h[k] <- h[k-U]; newest values in front.
#pragma unroll
        for (int k = CEP_M - 1; k >= UNROLL_U; --k) h[k] = h[k - UNROLL_U];
#pragma unroll
        for (int j = 0; j < UNROLL_U; ++j) h[UNROLL_U - 1 - j] = s[j];
        fn += (float)UNROLL_U;
    }
}

extern "C" void kernel_launch(void* const* d_in, const int* in_sizes, int n_in,
                              void* d_out, int out_size, void* d_ws, size_t ws_size,
                              hipStream_t stream) {
    const float* c = (const float*)d_in[0];
    float* out = (float*)d_out;
    cep2ir_kernel<<<BATCH / 256, 256, 0, stream>>>(c, out);
}

// Round 3
// 126.281 us; speedup vs baseline: 5.3272x; 5.3272x over previous
//
#include <hip/hip_runtime.h>
#include <math.h>

// CepstrumToImpulseResponse: h[0]=exp(c[0]); h[n] = (1/n) * sum_{m=1}^{min(n,99)} m*c[m]*h[n-m]
// B=65536, M=99, N=512. Output float32 [B, 512].
//
// Round-3 structure: 2 lanes per batch row (lane A: taps m=1..50, lane B: m=51..99).
//  - Uniform 58-slot register window hh[]: A frame hh[k]=h[n0+7-k], B frame hh[k]=h[n0-43-k].
//    Both lanes run the SAME static-index FMA loop: a += w[k]*hh[k+8-j], j=0..7, k=0..49.
//  - Per step: one __shfl_xor(partial,1) combines the halves; hn = sum * rcp(n).
//  - Per 8-step group: A passes hh[42..49] (= h[n0-35..n0-42]) to B's slots 0..7 (boundary),
//    then both shift the window by 8. All register indices compile-time static (no scratch).
//  - Outputs staged in LDS (128 rows x stride 129; banks (r+c)%32 conflict-free; col 128 =
//    dump slot for lane-B writes) and flushed every 128 columns with fully-coalesced,
//    64B-aligned row-segment stores (kills the RFO write-amplification seen in r1/r2).

#define NROWS   128   // rows per 256-thread block (2 lanes per row)
#define STRIDE  129   // LDS row stride in floats; col 128 is the dump column

__global__ __launch_bounds__(256)
void cep2ir_kernel(const float* __restrict__ c, float* __restrict__ out) {
    __shared__ float stage[NROWS * STRIDE];
    const int t = threadIdx.x;
    const int lrow = t >> 1;                 // local row 0..127
    const bool isA = (t & 1) == 0;
    const int rowbase = blockIdx.x * NROWS;
    const float* cb = c + (size_t)(rowbase + lrow) * 100;
    float* outb = out + (size_t)rowbase * 512;

    // Load 13 float4 = 52 floats: A covers c[0..51], B covers c[48..99].
    float e[52];
    {
        const float4* c4 = reinterpret_cast<const float4*>(cb);
        const int f4b = isA ? 0 : 12;
#pragma unroll
        for (int i = 0; i < 13; ++i) {
            const float4 v = c4[f4b + i];
            e[4 * i + 0] = v.x; e[4 * i + 1] = v.y;
            e[4 * i + 2] = v.z; e[4 * i + 3] = v.w;
        }
    }
    // Weights: A: w[k] = c[k+1]*(k+1), k=0..49. B: w[k] = c[51+k]*(51+k), k=0..48; w[49]=0.
    float w[50];
#pragma unroll
    for (int k = 0; k < 49; ++k)
        w[k] = (isA ? e[k + 1] : e[k + 3]) * (isA ? (float)(k + 1) : (float)(k + 51));
    w[49] = isA ? e[50] * 50.0f : 0.0f;

    const float h0 = expf(e[0]);  // only meaningful on lane A

    // History window, all slots static-indexed. Init: zeros; A seeds h[0] at slot 8.
    float hh[58];
#pragma unroll
    for (int k = 0; k < 58; ++k) hh[k] = 0.0f;
    hh[8] = isA ? h0 : 0.0f;

    // h0 -> stage col 0 (lane B writes the dump column).
    stage[lrow * STRIDE + (isA ? 0 : 128)] = h0;

    float fn = 1.0f;   // n at j=0 of current group
    int   ni = 1;
    float carry = 0.0f;

#pragma unroll 1
    for (int p = 0; p < 4; ++p) {
#pragma unroll 1
        for (int gg = 0; gg < 16; ++gg) {
            float bv[8];
#pragma unroll
            for (int j = 0; j < 8; ++j) {
                float a0 = 0.f, a1 = 0.f, a2 = 0.f, a3 = 0.f;
#pragma unroll
                for (int k = 0; k < 50; ++k) {
                    const float prod = w[k] * hh[k + 8 - j];
                    if ((k & 3) == 0) a0 += prod;
                    else if ((k & 3) == 1) a1 += prod;
                    else if ((k & 3) == 2) a2 += prod;
                    else a3 += prod;
                }
                const float asum = (a0 + a1) + (a2 + a3);
                const float tsum = asum + __shfl_xor(asum, 1);
                const float hn = tsum * __builtin_amdgcn_rcpf(fn + (float)j);
                if (j == 7 && gg == 15) {
                    carry = hn;  // n = 128*(p+1): col 0 of next phase (or dropped if p==3)
                } else {
                    const int col = (ni + j) & 127;
                    stage[lrow * STRIDE + (isA ? col : 128)] = hn;
                }
                hh[7 - j] = isA ? hn : hh[7 - j];  // only A's frame takes fresh outputs
            }
            // Boundary pass: A's hh[42..49] = h[n0-35..n0-42] -> B's next slots 0..7.
#pragma unroll
            for (int jj = 0; jj < 8; ++jj) bv[jj] = __shfl_xor(hh[42 + jj], 1);
            // Shift window by 8 (descending: sources untouched before use).
#pragma unroll
            for (int k = 57; k >= 8; --k) hh[k] = hh[k - 8];
#pragma unroll
            for (int jj = 0; jj < 8; ++jj) hh[jj] = bv[jj];  // A's copy is overwritten in-group
            fn += 8.0f;
            ni += 8;
        }
        __syncthreads();
        // Coalesced flush: 128 rows x 128 cols -> out[row][128p .. 128p+127].
#pragma unroll 1
        for (int i = 0; i < 64; ++i) {
            const int idx = i * 256 + t;
            const int r = idx >> 7;
            const int cc = idx & 127;
            outb[(size_t)r * 512 + p * 128 + cc] = stage[r * STRIDE + cc];
        }
        __syncthreads();
        if (p < 3) stage[lrow * STRIDE + (isA ? 0 : 128)] = carry;  // col 0 of next phase
    }
}

extern "C" void kernel_launch(void* const* d_in, const int* in_sizes, int n_in,
                              void* d_out, int out_size, void* d_ws, size_t ws_size,
                              hipStream_t stream) {
    const float* c = (const float*)d_in[0];
    float* out = (float*)d_out;
    // 2 lanes per row: 65536 rows * 2 / 256 = 512 blocks (2 per CU).
    cep2ir_kernel<<<512, 256, 0, stream>>>(c, out);
}

// Round 4
// 115.261 us; speedup vs baseline: 5.8365x; 1.0956x over previous
//
#include <hip/hip_runtime.h>
#include <math.h>

// CepstrumToImpulseResponse: h[0]=exp(c[0]); h[n] = (1/n) * sum_{m=1}^{min(n,99)} m*c[m]*h[n-m]
// B=65536, M=99, N=512. Output float32 [B, 512].
//
// 2 lanes per batch row (lane A: taps m=1..50, lane B: m=51..99); uniform 58-slot
// register window hh[] with all-static indexing; U=8 time unroll; LDS-staged
// coalesced output flush in 4 phases of 128 columns.
//
// Round-4: (a) amdgpu_waves_per_eu(2,2) -- round 3's VGPR_Count=88 proved the
// compiler targeted unusable occupancy (LDS caps at 2 waves/SIMD) and shuttled
// the ~130-float live set through AGPRs (hidden mov inflation). (b) xor-1
// shuffles via DPP quad_perm (1 VALU op) instead of ds_bpermute (2.03M LDS
// bank-conflict cycles, ~30cy on the serial chain). (c) rcp(n) hoisted to
// group top, off the chain. (d) A-only LDS stores at base+imm offsets.

#define NROWS   128   // rows per 256-thread block (2 lanes per row)
#define STRIDE  129   // LDS row stride in floats; slot 128 doubles as dump col

__device__ __forceinline__ float dpp_xor1(float x) {
    // quad_perm:[1,0,3,2] == swap lanes within pairs (xor 1)
    int r = __builtin_amdgcn_mov_dpp(__float_as_int(x), 0xB1, 0xF, 0xF, false);
    return __int_as_float(r);
}

__global__ __launch_bounds__(256)
__attribute__((amdgpu_waves_per_eu(2, 2)))
void cep2ir_kernel(const float* __restrict__ c, float* __restrict__ out) {
    __shared__ float stage[NROWS * STRIDE];
    const int t = threadIdx.x;
    const int lrow = t >> 1;                 // local row 0..127
    const bool isA = (t & 1) == 0;
    const int rowbase = blockIdx.x * NROWS;
    const float* cb = c + (size_t)(rowbase + lrow) * 100;
    float* outb = out + (size_t)rowbase * 512;

    // Load 13 float4 = 52 floats: A covers c[0..51], B covers c[48..99].
    float e[52];
    {
        const float4* c4 = reinterpret_cast<const float4*>(cb);
        const int f4b = isA ? 0 : 12;
#pragma unroll
        for (int i = 0; i < 13; ++i) {
            const float4 v = c4[f4b + i];
            e[4 * i + 0] = v.x; e[4 * i + 1] = v.y;
            e[4 * i + 2] = v.z; e[4 * i + 3] = v.w;
        }
    }
    // Weights: A: w[k] = c[k+1]*(k+1), k=0..49. B: w[k] = c[51+k]*(51+k), k=0..48; w[49]=0.
    float w[50];
#pragma unroll
    for (int k = 0; k < 49; ++k)
        w[k] = (isA ? e[k + 1] : e[k + 3]) * (isA ? (float)(k + 1) : (float)(k + 51));
    w[49] = isA ? e[50] * 50.0f : 0.0f;

    const float h0 = expf(e[0]);  // meaningful on lane A

    // History window: A frame hh[k]=h(n0+7-k), B frame hh[k]=h(n0-43-k). Static idx only.
    float hh[58];
#pragma unroll
    for (int k = 0; k < 58; ++k) hh[k] = 0.0f;
    hh[8] = isA ? h0 : 0.0f;

    if (isA) stage[lrow * STRIDE] = h0;   // col 0 of phase 0

    float fn = 1.0f;    // n at j=0 of current group
    float carry = 0.0f; // h(128*(p+1)) -> col 0 of next phase

#pragma unroll 1
    for (int p = 0; p < 4; ++p) {
        float* sp = &stage[lrow * STRIDE + 1];
#pragma unroll 1
        for (int gg = 0; gg < 16; ++gg) {
            // rcp(n) for the 8 steps: data-independent, hoisted off the chain.
            float rn[8];
#pragma unroll
            for (int j = 0; j < 8; ++j) rn[j] = __builtin_amdgcn_rcpf(fn + (float)j);

            float hn7 = 0.0f;
#pragma unroll
            for (int j = 0; j < 8; ++j) {
                float a0 = 0.f, a1 = 0.f, a2 = 0.f, a3 = 0.f;
#pragma unroll
                for (int k = 0; k < 50; ++k) {
                    const float prod = w[k] * hh[k + 8 - j];
                    if ((k & 3) == 0) a0 += prod;
                    else if ((k & 3) == 1) a1 += prod;
                    else if ((k & 3) == 2) a2 += prod;
                    else a3 += prod;
                }
                const float asum = (a0 + a1) + (a2 + a3);
                const float hn = (asum + dpp_xor1(asum)) * rn[j];
                if (isA) sp[j] = hn;               // gg==15,j==7 lands in dump col 128
                hh[7 - j] = isA ? hn : hh[7 - j];  // only A's frame takes fresh outputs
                if (j == 7) hn7 = hn;
            }
            carry = hn7;  // last group's value survives the phase

            // Boundary: A's hh[42..49] -> B's next slots 0..7 (via DPP pair-swap).
            float bv[8];
#pragma unroll
            for (int jj = 0; jj < 8; ++jj) bv[jj] = dpp_xor1(hh[42 + jj]);
            // Shift window by 8 (descending; sources untouched before use).
#pragma unroll
            for (int k = 57; k >= 8; --k) hh[k] = hh[k - 8];
#pragma unroll
            for (int jj = 0; jj < 8; ++jj) hh[jj] = bv[jj];  // A's copy overwritten in-group
            fn += 8.0f;
            sp += 8;
        }
        __syncthreads();
        // Coalesced flush: 128 rows x 128 cols -> out[row][128p .. 128p+127].
#pragma unroll 1
        for (int i = 0; i < 64; ++i) {
            const int idx = i * 256 + t;
            const int r = idx >> 7;
            const int cc = idx & 127;
            outb[(size_t)r * 512 + p * 128 + cc] = stage[r * STRIDE + cc];
        }
        __syncthreads();
        if (p < 3 && isA) stage[lrow * STRIDE] = carry;  // col 0 of next phase
    }
}

extern "C" void kernel_launch(void* const* d_in, const int* in_sizes, int n_in,
                              void* d_out, int out_size, void* d_ws, size_t ws_size,
                              hipStream_t stream) {
    const float* c = (const float*)d_in[0];
    float* out = (float*)d_out;
    // 2 lanes per row: 65536 rows * 2 / 256 = 512 blocks (2 per CU).
    cep2ir_kernel<<<512, 256, 0, stream>>>(c, out);
}

// Round 5
// 111.557 us; speedup vs baseline: 6.0303x; 1.0332x over previous
//
#include <hip/hip_runtime.h>
#include <math.h>

// CepstrumToImpulseResponse: h[0]=exp(c[0]); h[n] = (1/n) * sum_{m=1}^{min(n,99)} m*c[m]*h[n-m]
// B=65536, M=99, N=512. Output float32 [B, 512].
//
// 2 lanes per batch row (lane A: taps m=1..50, lane B: m=51..99); uniform 66-slot
// register window hh[] with all-static indexing; U=16 time unroll; xor-1 lane
// exchange via DPP quad_perm; LDS-staged coalesced output flush (4 phases x 128 cols).
//
// Round-5: U=8 -> 16 amortizes the per-group fixed costs (50 shift movs, boundary
// exchange, rcp block) over 2x steps: static FMA density 73% -> ~78%. Reduce tree
// 4 accs + 3 adds -> 2 accs + 1 add. __launch_bounds__(256,2) requests the full
// 256-VGPR budget that the LDS-capped occupancy (2 waves/SIMD) already implies.
//
// Index maps (verified): A frame hh[i] = h(n0+15-i); B frame hh[i] = h(n0-35-i).
// Step j reads hh[k+16-j] (k = 0..49): A -> h(n_j-(k+1)), B -> h(n_j-(51+k)).
// Fresh h(n0+j) -> slot 15-j (lane A only; B slots preserved via cndmask).
// Group end: bv[jj] = dpp_xor1(hh[34+jj]) = h(n0-19-jj) = B's next slots 0..15;
// shift hh[65..16] <- hh[49..0]; hh[0..15] <- bv (A's copies are dead).

#define NROWS   128   // rows per 256-thread block (2 lanes per row)
#define STRIDE  129   // LDS row stride in floats; slot 128 doubles as dump col

__device__ __forceinline__ float dpp_xor1(float x) {
    // quad_perm:[1,0,3,2] == swap lanes within pairs (xor 1)
    int r = __builtin_amdgcn_mov_dpp(__float_as_int(x), 0xB1, 0xF, 0xF, false);
    return __int_as_float(r);
}

__global__ __launch_bounds__(256, 2)
void cep2ir_kernel(const float* __restrict__ c, float* __restrict__ out) {
    __shared__ float stage[NROWS * STRIDE];
    const int t = threadIdx.x;
    const int lrow = t >> 1;                 // local row 0..127
    const bool isA = (t & 1) == 0;
    const int rowbase = blockIdx.x * NROWS;
    const float* cb = c + (size_t)(rowbase + lrow) * 100;
    float* outb = out + (size_t)rowbase * 512;

    // Load 13 float4 = 52 floats: A covers c[0..51], B covers c[48..99].
    float e[52];
    {
        const float4* c4 = reinterpret_cast<const float4*>(cb);
        const int f4b = isA ? 0 : 12;
#pragma unroll
        for (int i = 0; i < 13; ++i) {
            const float4 v = c4[f4b + i];
            e[4 * i + 0] = v.x; e[4 * i + 1] = v.y;
            e[4 * i + 2] = v.z; e[4 * i + 3] = v.w;
        }
    }
    // Weights: A: w[k] = c[k+1]*(k+1), k=0..49. B: w[k] = c[51+k]*(51+k), k=0..48; w[49]=0.
    float w[50];
#pragma unroll
    for (int k = 0; k < 49; ++k)
        w[k] = (isA ? e[k + 1] : e[k + 3]) * (isA ? (float)(k + 1) : (float)(k + 51));
    w[49] = isA ? e[50] * 50.0f : 0.0f;

    const float h0 = expf(e[0]);  // meaningful on lane A

    // History window (66 slots, static idx only). Zeros = h(negative); A seeds h(0) at slot 16.
    float hh[66];
#pragma unroll
    for (int k = 0; k < 66; ++k) hh[k] = 0.0f;
    hh[16] = isA ? h0 : 0.0f;

    if (isA) stage[lrow * STRIDE] = h0;   // col 0 of phase 0

    float fn = 1.0f;    // n at j=0 of current group
    float carry = 0.0f; // h(128*(p+1)) -> col 0 of next phase

#pragma unroll 1
    for (int p = 0; p < 4; ++p) {
        float* sp = &stage[lrow * STRIDE + 1];
#pragma unroll 1
        for (int gg = 0; gg < 8; ++gg) {
            // rcp(n) for the 16 steps: data-independent, off the serial chain.
            float rn[16];
#pragma unroll
            for (int j = 0; j < 16; ++j) rn[j] = __builtin_amdgcn_rcpf(fn + (float)j);

            float hnLast = 0.0f;
#pragma unroll
            for (int j = 0; j < 16; ++j) {
                float a0 = 0.f, a1 = 0.f;
#pragma unroll
                for (int k = 0; k < 50; ++k) {
                    const float prod = w[k] * hh[k + 16 - j];
                    if ((k & 1) == 0) a0 += prod; else a1 += prod;
                }
                const float asum = a0 + a1;
                const float hn = (asum + dpp_xor1(asum)) * rn[j];
                if (isA) sp[j] = hn;                 // gg==7,j==15 lands in dump col 128
                hh[15 - j] = isA ? hn : hh[15 - j];  // only A's frame takes fresh outputs
                if (j == 15) hnLast = hn;
            }
            carry = hnLast;  // last group's value survives the phase

            // Boundary: A's hh[34..49] (= h(n0-19..n0-34)) -> B's next slots 0..15.
            float bv[16];
#pragma unroll
            for (int jj = 0; jj < 16; ++jj) bv[jj] = dpp_xor1(hh[34 + jj]);
            // Shift window by 16 (descending; sources untouched before use).
#pragma unroll
            for (int k = 65; k >= 16; --k) hh[k] = hh[k - 16];
#pragma unroll
            for (int jj = 0; jj < 16; ++jj) hh[jj] = bv[jj];  // A's copies are dead
            fn += 16.0f;
            sp += 16;
        }
        __syncthreads();
        // Coalesced flush: 128 rows x 128 cols -> out[row][128p .. 128p+127].
#pragma unroll 1
        for (int i = 0; i < 64; ++i) {
            const int idx = i * 256 + t;
            const int r = idx >> 7;
            const int cc = idx & 127;
            outb[(size_t)r * 512 + p * 128 + cc] = stage[r * STRIDE + cc];
        }
        __syncthreads();
        if (p < 3 && isA) stage[lrow * STRIDE] = carry;  // col 0 of next phase
    }
}

extern "C" void kernel_launch(void* const* d_in, const int* in_sizes, int n_in,
                              void* d_out, int out_size, void* d_ws, size_t ws_size,
                              hipStream_t stream) {
    const float* c = (const float*)d_in[0];
    float* out = (float*)d_out;
    // 2 lanes per row: 65536 rows * 2 / 256 = 512 blocks (2 per CU).
    cep2ir_kernel<<<512, 256, 0, stream>>>(c, out);
}